// Round 7
// baseline (1085.059 us; speedup 1.0000x reference)
//
#include <hip/hip_runtime.h>
#include <math.h>

#define NCH   14595
#define WROW  14600          // row stride (floats) in transposed workspace
#define HR_C  13
#define IMG_H 512
#define IMG_W 512
#define BS    4

typedef float f32x2 __attribute__((ext_vector_type(2)));
typedef float f32x4 __attribute__((ext_vector_type(4)));

// param layout per lr-pixel row: [bias|W] per layer, starts:
// L0:0 (1920), L1:1920 (4160), L2:6080 (4160), L3:10240 (4160), L4:14400 (195)

__global__ __launch_bounds__(256) void transpose_params(const float* __restrict__ lp,
                                                        float* __restrict__ wsT) {
    __shared__ float tile[64][65];
    int bid = blockIdx.x;
    int pt = bid & 15;
    int t  = bid >> 4;
    int ct = t % 229;
    int b  = t / 229;
    int c0 = ct * 64, p0 = pt * 64;
    int tp = threadIdx.x & 63;
    int tr = threadIdx.x >> 6;
#pragma unroll
    for (int s = 0; s < 16; s++) {
        int c = c0 + tr + s * 4;
        if (c < NCH)
            tile[tr + s * 4][tp] = lp[((size_t)b * NCH + c) * 1024 + p0 + tp];
    }
    __syncthreads();
#pragma unroll
    for (int s = 0; s < 16; s++) {
        int p = p0 + tr + s * 4;
        int c = c0 + tp;
        if (c < NCH)
            wsT[((size_t)b * 1024 + p) * WROW + c] = tile[tp][tr + s * 4];
    }
}

// LDS-only barrier: never drains vmcnt (compiler's weight loads may stay in
// flight only within a layer; across the barrier it re-issues — fine).
__device__ __forceinline__ void block_sync_lds() {
    __builtin_amdgcn_sched_barrier(0);
    asm volatile("s_waitcnt lgkmcnt(0)" ::: "memory");
    __builtin_amdgcn_s_barrier();
    __builtin_amdgcn_sched_barrier(0);
}

// Hidden layer: acts via LDS (lgkm), weights via plain vector loads (vmcnt)
// from opacified pointer. Compiler schedules/pipelines everything.
template<int NCI>
__device__ __forceinline__ void layer_ws(const float* __restrict__ actT,
                                         const float* __restrict__ wop,
                                         int lstart, int o0,
                                         int px0, float acc[2][16]) {
    // bias init: 16 ch, uniform-valued vector loads
    {
        f32x4 b0 = *(const f32x4*)(wop + lstart + o0);
        f32x4 b1 = *(const f32x4*)(wop + lstart + o0 + 4);
        f32x4 b2 = *(const f32x4*)(wop + lstart + o0 + 8);
        f32x4 b3 = *(const f32x4*)(wop + lstart + o0 + 12);
#pragma unroll
        for (int j = 0; j < 4; j++) {
            acc[0][j]      = b0[j]; acc[1][j]      = b0[j];
            acc[0][4 + j]  = b1[j]; acc[1][4 + j]  = b1[j];
            acc[0][8 + j]  = b2[j]; acc[1][8 + j]  = b2[j];
            acc[0][12 + j] = b3[j]; acc[1][12 + j] = b3[j];
        }
    }
    const float* wk = wop + lstart + 64 + o0;
#pragma unroll 4
    for (int k = 0; k < NCI; k++) {
        f32x2 a  = *(const f32x2*)&actT[k * 128 + px0];
        f32x4 w0 = *(const f32x4*)(wk + (k << 6));
        f32x4 w1 = *(const f32x4*)(wk + (k << 6) + 4);
        f32x4 w2 = *(const f32x4*)(wk + (k << 6) + 8);
        f32x4 w3 = *(const f32x4*)(wk + (k << 6) + 12);
#pragma unroll
        for (int j = 0; j < 4; j++) {
            acc[0][j]      = fmaf(a.x, w0[j], acc[0][j]);
            acc[1][j]      = fmaf(a.y, w0[j], acc[1][j]);
            acc[0][4 + j]  = fmaf(a.x, w1[j], acc[0][4 + j]);
            acc[1][4 + j]  = fmaf(a.y, w1[j], acc[1][4 + j]);
            acc[0][8 + j]  = fmaf(a.x, w2[j], acc[0][8 + j]);
            acc[1][8 + j]  = fmaf(a.y, w2[j], acc[1][8 + j]);
            acc[0][12 + j] = fmaf(a.x, w3[j], acc[0][12 + j]);
            acc[1][12 + j] = fmaf(a.y, w3[j], acc[1][12 + j]);
        }
    }
}

// --------- slow fallback (no workspace) ----------
template<int NCI>
__device__ __forceinline__ void mlp_layer_slow(const float* __restrict__ actT,
                                               const float* __restrict__ lp_col,
                                               int loff, int o0,
                                               int px0, float acc[2][16]) {
#pragma unroll
    for (int j = 0; j < 16; j++) {
        float bv = lp_col[(size_t)(loff + o0 + j) << 10];
        acc[0][j] = bv; acc[1][j] = bv;
    }
#pragma unroll 2
    for (int k = 0; k < NCI; k++) {
        f32x2 a = *(const f32x2*)&actT[k * 128 + px0];
#pragma unroll
        for (int j = 0; j < 16; j++) {
            float w = lp_col[(size_t)(loff + 64 + (k << 6) + o0 + j) << 10];
            acc[0][j] = fmaf(a.x, w, acc[0][j]);
            acc[1][j] = fmaf(a.y, w, acc[1][j]);
        }
    }
}

template<bool USE_WS>
__global__ __launch_bounds__(256, 4) void asap_main(const float* __restrict__ hr,
                                                    const float* __restrict__ lp,
                                                    const float* __restrict__ wsT,
                                                    float* __restrict__ out) {
    __shared__ __align__(16) float actT[64 * 128];   // 32 KB, only LDS use

    // XCD-chunked swizzle (8192 blocks, 1024 per XCD, bijective)
    int bid0 = blockIdx.x;
    int bid  = ((bid0 & 7) << 10) | (bid0 >> 3);

    int half = bid & 1;
    int x    = (bid >> 1) & 31;
    int y    = (bid >> 6) & 31;
    int b    = bid >> 11;
    int tid  = threadIdx.x;
    int lane = tid & 63;
    int wv   = tid >> 6;                 // wave id 0..3
    int pix  = y * 32 + x;

    const float* wrow   = wsT + ((size_t)b * 1024 + pix) * WROW;
    const float* lp_col = lp + (size_t)b * NCH * 1024 + pix;

    // Opacify the weight pointer: forces it into VGPRs and defeats uniformity
    // analysis, so weight loads become global_load_dwordx4 (vmcnt queue,
    // compiler-counted + pipelined) instead of s_load (lgkmcnt, joint-drained
    // with LDS).
    const float* wop = wrow;
    asm("" : "+v"(wop));

    // ---- build inputs: hr channels + cosine coords ----
    {
        int Y0 = y * 16 + half * 8, X0 = x * 16;
        for (int t = tid; t < HR_C * 128; t += 256) {
            int c = t >> 7, p = t & 127;
            int row = p >> 4, kx = p & 15;
            actT[c * 128 + p] =
                hr[(((size_t)b * HR_C + c) * IMG_H + Y0 + row) * IMG_W + X0 + kx];
        }
        if (tid < 128) {
            int p = tid, row = p >> 4, kx = p & 15;
            int kyg = half * 8 + row;
            const float two_pi = 6.28318530717958647692f;
            int f = 16;
#pragma unroll
            for (int fi = 0; fi < 4; fi++) {
                float ax = two_pi * (float)(kx & (f - 1)) / (float)f;
                float ay = two_pi * (float)(kyg & (f - 1)) / (float)f;
                actT[(13 + 4 * fi + 0) * 128 + p] = cosf(ax);
                actT[(13 + 4 * fi + 1) * 128 + p] = sinf(ax);
                actT[(13 + 4 * fi + 2) * 128 + p] = cosf(ay);
                actT[(13 + 4 * fi + 3) * 128 + p] = sinf(ay);
                f >>= 1;
            }
        }
    }
    block_sync_lds();

    int o0  = wv << 4;                   // 16 out-ch per wave
    int px0 = lane << 1;                 // 2 px per lane
    float acc[2][16];

    auto writeback = [&]() {
#pragma unroll
        for (int j = 0; j < 16; j++) {
            f32x2 v;
            v.x = fmaxf(acc[0][j], 0.01f * acc[0][j]);
            v.y = fmaxf(acc[1][j], 0.01f * acc[1][j]);
            *(f32x2*)&actT[(o0 + j) * 128 + px0] = v;
        }
    };

    if (USE_WS) {
        layer_ws<29>(actT, wop, 0, o0, px0, acc);
        block_sync_lds(); writeback(); block_sync_lds();
        layer_ws<64>(actT, wop, 1920, o0, px0, acc);
        block_sync_lds(); writeback(); block_sync_lds();
        layer_ws<64>(actT, wop, 6080, o0, px0, acc);
        block_sync_lds(); writeback(); block_sync_lds();
        layer_ws<64>(actT, wop, 10240, o0, px0, acc);
        block_sync_lds(); writeback(); block_sync_lds();

        // ---- final layer: nci=64, nco=3, tanh; lanes 0..127 own a pixel ----
        if (tid < 128) {
            int p = tid;
            float s0 = wop[14400], s1 = wop[14401], s2 = wop[14402];
#pragma unroll 4
            for (int k = 0; k < 64; k++) {
                float a = actT[k * 128 + p];
                s0 = fmaf(a, wop[14403 + k * 3 + 0], s0);
                s1 = fmaf(a, wop[14403 + k * 3 + 1], s1);
                s2 = fmaf(a, wop[14403 + k * 3 + 2], s2);
            }
            int row = p >> 4, kx = p & 15;
            int Y = y * 16 + half * 8 + row, X = x * 16 + kx;
            size_t base = ((size_t)b * 3) * IMG_H * IMG_W + (size_t)Y * IMG_W + X;
            out[base]                             = tanhf(s0);
            out[base + (size_t)IMG_H * IMG_W]     = tanhf(s1);
            out[base + (size_t)2 * IMG_H * IMG_W] = tanhf(s2);
        }
    } else {
        mlp_layer_slow<29>(actT, lp_col, 0,     o0, px0, acc);
        block_sync_lds(); writeback(); block_sync_lds();
        mlp_layer_slow<64>(actT, lp_col, 1920,  o0, px0, acc);
        block_sync_lds(); writeback(); block_sync_lds();
        mlp_layer_slow<64>(actT, lp_col, 6080,  o0, px0, acc);
        block_sync_lds(); writeback(); block_sync_lds();
        mlp_layer_slow<64>(actT, lp_col, 10240, o0, px0, acc);
        block_sync_lds(); writeback(); block_sync_lds();
        if (tid < 128) {
            int p = tid;
            float s0 = lp_col[(size_t)14400 << 10];
            float s1 = lp_col[(size_t)14401 << 10];
            float s2 = lp_col[(size_t)14402 << 10];
#pragma unroll 4
            for (int k = 0; k < 64; k++) {
                float a = actT[k * 128 + p];
                s0 = fmaf(a, lp_col[(size_t)(14403 + k * 3 + 0) << 10], s0);
                s1 = fmaf(a, lp_col[(size_t)(14403 + k * 3 + 1) << 10], s1);
                s2 = fmaf(a, lp_col[(size_t)(14403 + k * 3 + 2) << 10], s2);
            }
            int row = p >> 4, kx = p & 15;
            int Y = y * 16 + half * 8 + row, X = x * 16 + kx;
            size_t base = ((size_t)b * 3) * IMG_H * IMG_W + (size_t)Y * IMG_W + X;
            out[base]                             = tanhf(s0);
            out[base + (size_t)IMG_H * IMG_W]     = tanhf(s1);
            out[base + (size_t)2 * IMG_H * IMG_W] = tanhf(s2);
        }
    }
}

extern "C" void kernel_launch(void* const* d_in, const int* in_sizes, int n_in,
                              void* d_out, int out_size, void* d_ws, size_t ws_size,
                              hipStream_t stream) {
    const float* hr = (const float*)d_in[0];
    const float* lp = (const float*)d_in[1];
    float* out = (float*)d_out;
    float* wsT = (float*)d_ws;

    size_t need = (size_t)BS * 1024 * WROW * sizeof(float);
    if (ws_size >= need) {
        transpose_params<<<BS * 229 * 16, 256, 0, stream>>>(lp, wsT);
        asap_main<true><<<8192, 256, 0, stream>>>(hr, lp, wsT, out);
    } else {
        asap_main<false><<<8192, 256, 0, stream>>>(hr, lp, wsT, out);
    }
}